// Round 11
// baseline (301.838 us; speedup 1.0000x reference)
//
#include <hip/hip_runtime.h>

#define FIN 128
#define FH  16
#define FO  64
#define GB  128        // nodes per bucket (pow2: bucket = dst>>7)
#define MAXNB 1024     // max buckets (N <= 131072)
#define CHUNK 8192     // edges per block in bscatter

__device__ __forceinline__ unsigned pack_bf16x2(float a, float b) {
    unsigned ua = __float_as_uint(a), ub = __float_as_uint(b);
    ua = (ua + 0x7fffu + ((ua >> 16) & 1u)) >> 16;          // RNE
    ub = (ub + 0x7fffu + ((ub >> 16) & 1u)) >> 16;
    return ua | (ub << 16);
}

__device__ __forceinline__ float2 unpack_bf16x2(unsigned u) {
    float2 r;
    r.x = __uint_as_float(u << 16);
    r.y = __uint_as_float(u & 0xffff0000u);
    return r;
}

// ---------- A1: bucket histogram (LDS-aggregated), 1024 threads ----------
__global__ __launch_bounds__(1024) void k_bhist(const int* __restrict__ dst,
                                                int* __restrict__ bcnt, int E, int nb) {
    __shared__ int h[MAXNB];
    int t = threadIdx.x;
    if (t < nb) h[t] = 0;
    __syncthreads();
    int stride = gridDim.x * 1024;
    for (int e = blockIdx.x * 1024 + t; e < E; e += stride)
        atomicAdd(&h[dst[e] >> 7], 1);
    __syncthreads();
    if (t < nb && h[t]) atomicAdd(&bcnt[t], h[t]);
}

// ---------- A2: single-block exclusive scan of bucket counts ----------
__global__ __launch_bounds__(1024) void k_bscan(const int* __restrict__ bcnt,
                                                int* __restrict__ bstart,
                                                int* __restrict__ bfill, int nb) {
    __shared__ int s[1024];
    int t = threadIdx.x;
    int v = (t < nb) ? bcnt[t] : 0;
    s[t] = v;
    __syncthreads();
    for (int off = 1; off < 1024; off <<= 1) {
        int u = (t >= off) ? s[t - off] : 0;
        __syncthreads();
        s[t] += u;
        __syncthreads();
    }
    if (t < nb) { bstart[t] = s[t] - v; bfill[t] = s[t] - v; }
    if (t == nb - 1) bstart[nb] = s[t];
}

// ---------- A3: chunk-local LDS bucket-sort, 1024 threads (1 bucket/thread) ----------
// pack: (dst & 127) << 17 | src   (src < 2^17)
__global__ __launch_bounds__(1024) void k_bscatter(const int* __restrict__ src,
                                                   const int* __restrict__ dst,
                                                   int* __restrict__ bfill,
                                                   int* __restrict__ bedge, int E) {
    __shared__ int h[MAXNB];      // chunk bucket counts -> fill counters (4 KB)
    __shared__ int scanp[1024];   // 4 KB
    __shared__ int stage[CHUNK];  // 32 KB
    int t = threadIdx.x;
    int c0 = blockIdx.x * CHUNK;
    int c1 = min(c0 + CHUNK, E);

    h[t] = 0;
    __syncthreads();
    for (int e = c0 + t; e < c1; e += 1024)
        atomicAdd(&h[dst[e] >> 7], 1);
    __syncthreads();

    int a = h[t];
    scanp[t] = a;
    __syncthreads();
    for (int off = 1; off < 1024; off <<= 1) {
        int u = (t >= off) ? scanp[t - off] : 0;
        __syncthreads();
        scanp[t] += u;
        __syncthreads();
    }
    int lo = scanp[t] - a;
    int hi = lo + a;

    int g = 0;
    if (a) g = atomicAdd(&bfill[t], a) - lo;
    h[t] = lo;
    __syncthreads();

    for (int e = c0 + t; e < c1; e += 1024) {
        int d = dst[e];
        int p = atomicAdd(&h[d >> 7], 1);
        stage[p] = ((d & 127) << 17) | src[e];
    }
    __syncthreads();

    for (int p = lo; p < hi; ++p) bedge[g + p] = stage[p];
}

// ---------- B: per-bucket node sort (stage-free): bedge -> sorted_src + CSR + dinv ----------
__global__ __launch_bounds__(256) void k_nsort(const int* __restrict__ bstart,
                                               const int* __restrict__ bedge,
                                               int* __restrict__ sorted_src,
                                               int* __restrict__ counts,
                                               int* __restrict__ row_start,
                                               float* __restrict__ dinv, int N) {
    __shared__ int hist[GB];
    __shared__ int fill[GB];
    int t = threadIdx.x, b = blockIdx.x;
    int base = b << 7;
    int nn = min(GB, N - base);
    if (nn <= 0) return;
    int ebeg = bstart[b], eend = bstart[b + 1];
    if (t < GB) hist[t] = 0;
    __syncthreads();
    for (int e = ebeg + t; e < eend; e += 256)
        atomicAdd(&hist[bedge[e] >> 17], 1);
    __syncthreads();
    int c = (t < GB) ? hist[t] : 0;
    for (int off = 1; off < GB; off <<= 1) {
        int u = (t < GB && t >= off) ? hist[t - off] : 0;
        __syncthreads();
        if (t < GB) hist[t] += u;
        __syncthreads();
    }
    int excl = (t < GB) ? hist[t] - c : 0;
    if (t < nn) {
        counts[base + t] = c;
        row_start[base + t] = ebeg + excl;
        dinv[base + t] = rsqrtf((float)(c + 1));
        fill[t] = ebeg + excl;
    }
    __syncthreads();
    for (int e = ebeg + t; e < eend; e += 256) {
        int v = bedge[e];
        int p = atomicAdd(&fill[v >> 17], 1);
        sorted_src[p] = v & 0x1FFFF;
    }
}

// ---------- layer 1 transform: hs1 = bf16((x @ W1) * dinv) ----------
__global__ __launch_bounds__(256) void k_gemm1(const float* __restrict__ x,
                                               const float* __restrict__ W1,
                                               const float* __restrict__ dinv,
                                               unsigned* __restrict__ hs1u, int n) {
    __shared__ float w[FIN * FH];  // 8 KB
    int t = threadIdx.x;
    for (int i = t; i < FIN * FH; i += 256) w[i] = W1[i];
    __syncthreads();
    int r = t >> 4, j = t & 15;
    int row = blockIdx.x * 16 + r;
    if (row >= n) return;
    const float* xr = x + (long long)row * FIN;
    float acc = 0.0f;
#pragma unroll 8
    for (int k = 0; k < FIN; ++k) acc = fmaf(xr[k], w[k * FH + j], acc);
    float v = acc * dinv[row];
    float v_hi = __shfl_xor(v, 1, 64);   // partner feature j^1
    if ((j & 1) == 0) hs1u[row * 8 + (j >> 1)] = pack_bf16x2(v, v_hi);
}

// ---------- layer 1 gather (uint2, ss-prefetch) + relu + bias, pre-scaled ----------
// 16 groups of 4 lanes; lane f4 covers features 4f4..4f4+3 (one uint2)
__global__ __launch_bounds__(256) void k_gather1(const int* __restrict__ rs,
                                                 const int* __restrict__ cnt,
                                                 const int* __restrict__ ss,
                                                 const uint2* __restrict__ hs1u,
                                                 const float* __restrict__ dinv,
                                                 const float* __restrict__ b1,
                                                 uint2* __restrict__ h1su, int n) {
    int t = threadIdx.x;
    int lane = t & 63, g4 = lane >> 2, f4 = lane & 3;
    int node = blockIdx.x * 4 + (t >> 6);
    if (node >= n) return;
    int beg = rs[node], end = beg + cnt[node];
    float a0 = 0.f, a1 = 0.f, a2 = 0.f, a3 = 0.f;
    for (int e = beg; e < end; e += 64) {
        int m = end - e; if (m > 64) m = 64;
        int myss = (lane < m) ? ss[e + lane] : 0;
        int jmax = (m + 15) >> 4;
#pragma unroll 4
        for (int j = 0; j < jmax; ++j) {
            int idx = j * 16 + g4;
            int s = __shfl(myss, idx, 64);
            if (idx < m) {
                uint2 u = hs1u[s * 4 + f4];
                float2 pa = unpack_bf16x2(u.x), pb = unpack_bf16x2(u.y);
                a0 += pa.x; a1 += pa.y; a2 += pb.x; a3 += pb.y;
            }
        }
    }
#pragma unroll
    for (int off = 4; off <= 32; off <<= 1) {
        a0 += __shfl_xor(a0, off, 64);
        a1 += __shfl_xor(a1, off, 64);
        a2 += __shfl_xor(a2, off, 64);
        a3 += __shfl_xor(a3, off, 64);
    }
    uint2 su = hs1u[node * 4 + f4];  // self-loop
    float2 sa = unpack_bf16x2(su.x), sb = unpack_bf16x2(su.y);
    a0 += sa.x; a1 += sa.y; a2 += sb.x; a3 += sb.y;
    float di = dinv[node];
    float v0 = fmaxf(fmaf(di, a0, b1[4 * f4 + 0]), 0.f) * di;
    float v1 = fmaxf(fmaf(di, a1, b1[4 * f4 + 1]), 0.f) * di;
    float v2 = fmaxf(fmaf(di, a2, b1[4 * f4 + 2]), 0.f) * di;
    float v3 = fmaxf(fmaf(di, a3, b1[4 * f4 + 3]), 0.f) * di;
    if (lane < 4) {
        uint2 o;
        o.x = pack_bf16x2(v0, v1);
        o.y = pack_bf16x2(v2, v3);
        h1su[node * 4 + f4] = o;
    }
}

// ---------- layer 2: uint2 gather + (g @ W2)*dinv + b2 -> log_softmax ----------
__global__ __launch_bounds__(256) void k_agg2f(const int* __restrict__ rs,
                                               const int* __restrict__ cnt,
                                               const int* __restrict__ ss,
                                               const uint2* __restrict__ h1su,
                                               const float* __restrict__ dinv,
                                               const float* __restrict__ W2,
                                               const float* __restrict__ b2,
                                               float* __restrict__ out, int n) {
    int t = threadIdx.x;
    int lane = t & 63, g4 = lane >> 2, f4 = lane & 3;
    int node = blockIdx.x * 4 + (t >> 6);
    if (node >= n) return;
    float w[FH];  // W2 column `lane`
#pragma unroll
    for (int j = 0; j < FH; ++j) w[j] = W2[j * FO + lane];
    int beg = rs[node], end = beg + cnt[node];
    float a0 = 0.f, a1 = 0.f, a2 = 0.f, a3 = 0.f;
    for (int e = beg; e < end; e += 64) {
        int m = end - e; if (m > 64) m = 64;
        int myss = (lane < m) ? ss[e + lane] : 0;
        int jmax = (m + 15) >> 4;
#pragma unroll 4
        for (int j = 0; j < jmax; ++j) {
            int idx = j * 16 + g4;
            int s = __shfl(myss, idx, 64);
            if (idx < m) {
                uint2 u = h1su[s * 4 + f4];
                float2 pa = unpack_bf16x2(u.x), pb = unpack_bf16x2(u.y);
                a0 += pa.x; a1 += pa.y; a2 += pb.x; a3 += pb.y;
            }
        }
    }
#pragma unroll
    for (int off = 4; off <= 32; off <<= 1) {
        a0 += __shfl_xor(a0, off, 64);
        a1 += __shfl_xor(a1, off, 64);
        a2 += __shfl_xor(a2, off, 64);
        a3 += __shfl_xor(a3, off, 64);
    }
    uint2 su = h1su[node * 4 + f4];  // self-loop
    float2 sa = unpack_bf16x2(su.x), sb = unpack_bf16x2(su.y);
    a0 += sa.x; a1 += sa.y; a2 += sb.x; a3 += sb.y;
    // lane f4 holds g[4f4..4f4+3]; transform 16 -> 64
    float o = 0.f;
#pragma unroll
    for (int j = 0; j < 4; ++j) {
        o = fmaf(__shfl(a0, j, 4), w[4 * j + 0], o);
        o = fmaf(__shfl(a1, j, 4), w[4 * j + 1], o);
        o = fmaf(__shfl(a2, j, 4), w[4 * j + 2], o);
        o = fmaf(__shfl(a3, j, 4), w[4 * j + 3], o);
    }
    float v = fmaf(dinv[node], o, b2[lane]);
    float m = v;
#pragma unroll
    for (int off = 32; off >= 1; off >>= 1) m = fmaxf(m, __shfl_xor(m, off, 64));
    float ex = __expf(v - m);
#pragma unroll
    for (int off = 32; off >= 1; off >>= 1) ex += __shfl_xor(ex, off, 64);
    out[node * FO + lane] = v - m - __logf(ex);
}

extern "C" void kernel_launch(void* const* d_in, const int* in_sizes, int n_in,
                              void* d_out, int out_size, void* d_ws, size_t ws_size,
                              hipStream_t stream) {
    const float* x  = (const float*)d_in[0];
    const int*   ei = (const int*)d_in[1];
    const float* W1 = (const float*)d_in[2];
    const float* b1 = (const float*)d_in[3];
    const float* W2 = (const float*)d_in[4];
    const float* b2 = (const float*)d_in[5];
    float* out = (float*)d_out;

    int N = in_sizes[0] / FIN;   // 100000
    int E = in_sizes[1] / 2;     // 3200000
    const int* src = ei;
    const int* dst = ei + E;
    int nb = (N + GB - 1) / GB;  // 782

    // workspace (4B units), bf16 arrays first for 8B alignment:
    // hs1u[8N] | h1su[8N] | dinv[N] | bcnt[1024] | bstart[1025] | bfill[1024]
    //   | counts[N] | row_start[N] | sorted_src[E] | bedge[E]
    unsigned* hs1u  = (unsigned*)d_ws;
    unsigned* h1su  = hs1u + 8LL * N;
    float* dinv     = (float*)(h1su + 8LL * N);
    int* bcnt       = (int*)(dinv + N);
    int* bstart     = bcnt + MAXNB;
    int* bfill      = bstart + MAXNB + 1;
    int* counts     = bfill + MAXNB;
    int* row_start  = counts + N;
    int* sorted_src = row_start + N;
    int* bedge      = sorted_src + E;

    hipMemsetAsync(bcnt, 0, MAXNB * sizeof(int), stream);
    k_bhist<<<256, 1024, 0, stream>>>(dst, bcnt, E, nb);
    k_bscan<<<1, 1024, 0, stream>>>(bcnt, bstart, bfill, nb);
    k_bscatter<<<(E + CHUNK - 1) / CHUNK, 1024, 0, stream>>>(src, dst, bfill, bedge, E);
    k_nsort<<<nb, 256, 0, stream>>>(bstart, bedge, sorted_src, counts, row_start, dinv, N);

    k_gemm1<<<(N + 15) / 16, 256, 0, stream>>>(x, W1, dinv, hs1u, N);
    k_gather1<<<(N + 3) / 4, 256, 0, stream>>>(row_start, counts, sorted_src,
                                               (const uint2*)hs1u, dinv, b1, (uint2*)h1su, N);
    k_agg2f<<<(N + 3) / 4, 256, 0, stream>>>(row_start, counts, sorted_src,
                                             (const uint2*)h1su, dinv, W2, b2, out, N);
}